// Round 10
// baseline (107.849 us; speedup 1.0000x reference)
//
#include <hip/hip_runtime.h>
#include <stdint.h>

#define NND 2048   // nodes
#define NE  32     // embed
#define NH  4      // heads
#define HDIM 16    // head dim
#define NB  8      // batch

typedef __attribute__((ext_vector_type(4))) float f32x4;
typedef _Float16 f16x8 __attribute__((ext_vector_type(8)));
typedef _Float16 h16x2 __attribute__((ext_vector_type(2)));
typedef __fp16 fp16x2 __attribute__((ext_vector_type(2)));

#define MFMAH(a,b,c) __builtin_amdgcn_mfma_f32_16x16x32_f16(a,b,c,0,0,0)

// ---------------- workspace layout (in float units) ----------------
static constexpr size_t OFF_QF    = 0;
static constexpr size_t OFF_KF    = 524288;
static constexpr size_t OFF_VT    = 1048576;
static constexpr size_t OFF_O     = 1572864;
static constexpr size_t OFF_R     = 2621440;
static constexpr size_t OFF_C     = 3670016;           // 65536
static constexpr size_t OFF_WQT   = 3866624;           // 524288
static constexpr size_t OFF_WBF   = 4390912;           // 32768
static constexpr size_t OFF_MT2   = 4424192;           // maskT2: [32 nb][64 u][64 n] u32 = 131072 f
static constexpr size_t OFF_MM    = 4555264;           // maskM: 131072 f
static constexpr size_t OFF_GP    = 4686336;           // gpart: [8 b][32 nc][64] = 16384 f

// ---------------- helpers ----------------
__device__ __forceinline__ uint32_t f2h2(float a, float b) {
    union { _Float16 h[2]; uint32_t u; } x;
    x.h[0] = (_Float16)a; x.h[1] = (_Float16)b; return x.u;
}
__device__ __forceinline__ uint32_t pkh(float a, float b) {
    union { fp16x2 h; uint32_t u; } x;
    x.h = __builtin_amdgcn_cvt_pkrtz(a, b); return x.u;
}
union U4H8 { uint4 u; f16x8 h; };
union U1H2 { uint32_t u; h16x2 h; };

#define ONE2 0x3C003C00u

// ---------------- QKV projection -> f16 layouts ----------------
__global__ __launch_bounds__(64) void qkv_kernel(
    const float* __restrict__ act, const float* __restrict__ embed,
    const float* __restrict__ Wq, const float* __restrict__ bq,
    const float* __restrict__ Wk, const float* __restrict__ bk,
    const float* __restrict__ Wv, const float* __restrict__ bv,
    ushort* __restrict__ Qf, ushort* __restrict__ Kf, ushort* __restrict__ Vt)
{
    const int blk = blockIdx.x;          // 1024 = 8 b * 128 chunks of 16 nodes
    const int b = blk >> 7, nc = blk & 127;
    const int j = threadIdx.x;           // channel 0..63

    float wq[NE], wk[NE], wv[NE];
    const float4* Wq4 = (const float4*)Wq;
    const float4* Wk4 = (const float4*)Wk;
    const float4* Wv4 = (const float4*)Wv;
#pragma unroll
    for (int t = 0; t < 8; ++t) {
        float4 a4 = Wq4[j * 8 + t];
        wq[4*t] = a4.x; wq[4*t+1] = a4.y; wq[4*t+2] = a4.z; wq[4*t+3] = a4.w;
        float4 b4 = Wk4[j * 8 + t];
        wk[4*t] = b4.x; wk[4*t+1] = b4.y; wk[4*t+2] = b4.z; wk[4*t+3] = b4.w;
        float4 c4 = Wv4[j * 8 + t];
        wv[4*t] = c4.x; wv[4*t+1] = c4.y; wv[4*t+2] = c4.z; wv[4*t+3] = c4.w;
    }
    const float bqj = bq[j], bkj = bk[j], bvj = bv[j];

    __shared__ float x[16][33];
    const float4* E4 = (const float4*)(embed + (size_t)nc * 16 * NE);
#pragma unroll
    for (int tt = 0; tt < 2; ++tt) {
        int t = tt * 64 + j;
        float4 e4 = E4[t];
        int row = t >> 3, col = (t & 7) * 4;
        float a = act[(size_t)b * NND + nc * 16 + row];
        x[row][col+0] = e4.x * a; x[row][col+1] = e4.y * a;
        x[row][col+2] = e4.z * a; x[row][col+3] = e4.w * a;
    }
    __syncthreads();

    __shared__ float qs[16][65], ks[16][65], vs[16][65];
    for (int ii = 0; ii < 16; ++ii) {
        float q = bqj, k = bkj, v = bvj;
#pragma unroll
        for (int e = 0; e < NE; ++e) {
            float xe = x[ii][e];
            q = fmaf(wq[e], xe, q);
            k = fmaf(wk[e], xe, k);
            v = fmaf(wv[e], xe, v);
        }
        qs[ii][j] = q * 0.25f;   // fold 1/sqrt(HD)
        ks[ii][j] = k;
        vs[ii][j] = v;
    }
    __syncthreads();

    const int c = j >> 4, ii = j & 15;
    {
        size_t row = ((size_t)(b*NH + c) << 11) + (nc << 4) + ii;
        uint32_t pk[8], pq[8];
#pragma unroll
        for (int t = 0; t < 8; ++t) {
            pk[t] = f2h2(ks[ii][c*16 + 2*t], ks[ii][c*16 + 2*t + 1]);
            pq[t] = f2h2(qs[ii][c*16 + 2*t], qs[ii][c*16 + 2*t + 1]);
        }
        uint4* dk = (uint4*)(Kf + row * 16);
        dk[0] = make_uint4(pk[0], pk[1], pk[2], pk[3]);
        dk[1] = make_uint4(pk[4], pk[5], pk[6], pk[7]);
        uint4* dq = (uint4*)(Qf + row * 16);
        dq[0] = make_uint4(pq[0], pq[1], pq[2], pq[3]);
        dq[1] = make_uint4(pq[4], pq[5], pq[6], pq[7]);
    }
    {
        uint32_t ph[8];
#pragma unroll
        for (int t = 0; t < 8; ++t)
            ph[t] = f2h2(vs[2*t][j], vs[2*t + 1][j]);
        size_t rowv = (((size_t)(b*NH + c) << 4) + ii) * 2048 + (nc << 4);
        uint4* dh = (uint4*)(Vt + rowv);
        dh[0] = make_uint4(ph[0], ph[1], ph[2], ph[3]);
        dh[1] = make_uint4(ph[4], ph[5], ph[6], ph[7]);
    }
}

// ---------------- adjacency -> maskT2 (attn) + maskM (colsum) ----------------
__global__ __launch_bounds__(256) void mask_kernel(
    const int* __restrict__ adj, uint32_t* __restrict__ maskT2,
    uint32_t* __restrict__ maskM)
{
    const int nb = blockIdx.x >> 5, mb = blockIdx.x & 31;
    const int n0 = nb * 64, m0 = mb * 64;
    __shared__ unsigned char ld[64][68];
    const int t = threadIdx.x;
    const int r = t >> 2, cs = (t & 3) * 16;
    const int4* src = (const int4*)(adj + (size_t)(n0 + r) * 2048 + m0 + cs);
    int4 a0 = src[0], a1 = src[1], a2 = src[2], a3 = src[3];
    unsigned char* dst = &ld[r][cs];
    dst[0]=a0.x!=0; dst[1]=a0.y!=0; dst[2]=a0.z!=0; dst[3]=a0.w!=0;
    dst[4]=a1.x!=0; dst[5]=a1.y!=0; dst[6]=a1.z!=0; dst[7]=a1.w!=0;
    dst[8]=a2.x!=0; dst[9]=a2.y!=0; dst[10]=a2.z!=0; dst[11]=a2.w!=0;
    dst[12]=a3.x!=0; dst[13]=a3.y!=0; dst[14]=a3.z!=0; dst[15]=a3.w!=0;
    __syncthreads();
    const int wv = t >> 6, lane = t & 63;
#pragma unroll 4
    for (int q = 0; q < 16; ++q) {
        int rr = wv * 16 + q;
        unsigned long long bm = __ballot(ld[rr][lane] != 0);
        if (lane == 0) {
            maskT2[(size_t)nb * 4096 + (size_t)(m0 >> 5) * 64 + rr]       = (uint32_t)bm;
            maskT2[(size_t)nb * 4096 + (size_t)((m0 >> 5) + 1) * 64 + rr] = (uint32_t)(bm >> 32);
        }
    }
#pragma unroll 4
    for (int q = 0; q < 16; ++q) {
        int cc = wv * 16 + q;
        unsigned long long bm = __ballot(ld[lane][cc] != 0);
        if (lane == 0) {
            maskM[(size_t)(n0 >> 5) * 2048 + m0 + cc]       = (uint32_t)bm;
            maskM[(size_t)((n0 >> 5) + 1) * 2048 + m0 + cc] = (uint32_t)(bm >> 32);
        }
    }
}

// ---------------- fused attention: group-of-4 LDS staging, double-buffered ----------------
// l via VALU: combined popc per group (ones part) + packed f16 sums of the
// masked tf fragment (s part) + 2 shfl_xor at the end. Mask words and LUT
// expansions for all 4 chunks hoisted to group top (off the chunk chain).
__global__ __launch_bounds__(256) void attn_a_kernel(
    const ushort* __restrict__ Qf, const ushort* __restrict__ Kf,
    const ushort* __restrict__ Vt, const uint32_t* __restrict__ maskT2,
    float* __restrict__ O, ushort* __restrict__ WQT, ushort* __restrict__ wbf)
{
    const int bid = blockIdx.x;
    const int bh   = ((bid & 7) << 2) | ((bid >> 3) & 3);   // XCD-local bh
    const int nblk = bid >> 5;
    const int tt = threadIdx.x;
    const int wv = tt >> 6, lane = tt & 63;
    const int i = lane & 15, g = lane >> 4;
    const int g8 = g << 3;
    const int n = nblk * 64 + wv * 16 + i;
    const int fi = ((i >> 2) << 3) | (i & 3);
    const int koff = (g & 1) * 8;

    __shared__ ushort Kg[2][2048];       // 128 rows x 16 ushorts, linear
    __shared__ ushort Vg[2][2176];       // 16 d x 136 ushorts (128 m + 8 pad)
    __shared__ uint32_t Mg[2][256];      // 4 chunks x 64 n-words
    __shared__ uint2 LUT[16];
    __shared__ ushort twq[16][68];

    if (tt < 16) {
        uint32_t v = tt;
        LUT[v] = make_uint2(
            ((v & 1u) ? 0xFFFFu : 0u) | ((v & 2u) ? 0xFFFF0000u : 0u),
            ((v & 4u) ? 0xFFFFu : 0u) | ((v & 8u) ? 0xFFFF0000u : 0u));
    }

    const ushort* Kb = Kf + (((size_t)bh << 11) << 4);
    const ushort* ksrc = Kb + tt * 8;                                        // + m0*16/group
    const ushort* vsrc = Vt + (((size_t)bh * 16 + (tt & 15)) << 11) + ((tt >> 4) << 3); // + m0/group
    const uint32_t* msrc = maskT2 + (size_t)nblk * 4096;                     // + grp*256 + tt
    const int vdst = (tt & 15) * 136 + ((tt >> 4) << 3);

    U4H8 qf; qf.u = make_uint4(0,0,0,0);
    if (g < 2) qf.u = *(const uint4*)(Qf + ((((size_t)bh << 11) + n) << 4) + koff);
    f32x4 oacc = {0.f,0.f,0.f,0.f};
    float lsum = 0.f;
    const f32x4 zc = {0.f,0.f,0.f,0.f};

    // prologue: stage group 0
    uint4 rk = *(const uint4*)ksrc;
    uint4 rv = *(const uint4*)vsrc;
    uint32_t rm = msrc[tt];
    *(uint4*)&Kg[0][tt * 8] = rk;
    *(uint4*)&Vg[0][vdst] = rv;
    Mg[0][tt] = rm;
    __syncthreads();

    const int mi = (wv << 4) + i;
    for (int grp = 0; grp < 16; ++grp) {
        const int buf = grp & 1;
        if (grp < 15) {   // issue next-group loads first (hide under compute)
            const int m0 = (grp + 1) << 7;
            rk = *(const uint4*)(ksrc + ((size_t)m0 << 4));
            rv = *(const uint4*)(vsrc + m0);
            rm = msrc[(grp + 1) * 256 + tt];
        }
        // hoist mask words + LUT expansions for all 4 chunks
        const uint32_t mg0 = Mg[buf][mi]       >> g8;
        const uint32_t mg1 = Mg[buf][64 + mi]  >> g8;
        const uint32_t mg2 = Mg[buf][128 + mi] >> g8;
        const uint32_t mg3 = Mg[buf][192 + mi] >> g8;
        const uint2 e0a = LUT[mg0 & 15u], e0b = LUT[(mg0 >> 4) & 15u];
        const uint2 e1a = LUT[mg1 & 15u], e1b = LUT[(mg1 >> 4) & 15u];
        const uint2 e2a = LUT[mg2 & 15u], e2b = LUT[(mg2 >> 4) & 15u];
        const uint2 e3a = LUT[mg3 & 15u], e3b = LUT[(mg3 >> 4) & 15u];
        lsum += (float)__popc((mg0 & 0xFFu) | ((mg1 & 0xFFu) << 8)
                            | ((mg2 & 0xFFu) << 16) | ((mg3 & 0xFFu) << 24));

#define CHUNK(J, EA, EB) do { \
            U4H8 ka, kb, vh; \
            ka.u = *(const uint4*)&Kg[buf][(((J) * 32 + fi) << 4) + koff]; \
            kb.u = *(const uint4*)&Kg[buf][(((J) * 32 + fi + 4) << 4) + koff]; \
            vh.u = *(const uint4*)&Vg[buf][i * 136 + (J) * 32 + g8]; \
            f32x4 ca = MFMAH(ka.h, qf.h, zc); \
            f32x4 cb = MFMAH(kb.h, qf.h, zc); \
            U4H8 mf, tf; \
            mf.u.x = EA.x & ONE2;  mf.u.y = EA.y & ONE2; \
            mf.u.z = EB.x & ONE2;  mf.u.w = EB.y & ONE2; \
            tf.u.x = pkh(ca[0], ca[1]) & EA.x; \
            tf.u.y = pkh(ca[2], ca[3]) & EA.y; \
            tf.u.z = pkh(cb[0], cb[1]) & EB.x; \
            tf.u.w = pkh(cb[2], cb[3]) & EB.y; \
            U1H2 h0, h1, h2, h3, hs; \
            h0.u = tf.u.x; h1.u = tf.u.y; h2.u = tf.u.z; h3.u = tf.u.w; \
            hs.h = (h0.h + h1.h) + (h2.h + h3.h); \
            lsum += (float)hs.h[0] + (float)hs.h[1]; \
            oacc = MFMAH(vh.h, mf.h, oacc); \
            oacc = MFMAH(vh.h, tf.h, oacc); \
        } while (0)

        CHUNK(0, e0a, e0b);
        CHUNK(1, e1a, e1b);
        CHUNK(2, e2a, e2b);
        CHUNK(3, e3a, e3b);
#undef CHUNK

        if (grp < 15) {   // write staged data into the other buffer
            *(uint4*)&Kg[buf ^ 1][tt * 8] = rk;
            *(uint4*)&Vg[buf ^ 1][vdst] = rv;
            Mg[buf ^ 1][tt] = rm;
        }
        __syncthreads();
    }

    lsum += __shfl_xor(lsum, 16);
    lsum += __shfl_xor(lsum, 32);
    const float w = 1.0f / lsum;
    f32x4 ov;
    ov[0] = oacc[0] * w; ov[1] = oacc[1] * w;
    ov[2] = oacc[2] * w; ov[3] = oacc[3] * w;
    *(f32x4*)(O + ((((size_t)bh << 11) + n) << 4) + (g << 2)) = ov;
    if (g == 0) {
        union { _Float16 h; ushort s; } cw; cw.h = (_Float16)(w * 256.0f);
        wbf[((size_t)bh << 11) + n] = cw.s;
    }
    // WQT = 256*w*q, transposed to [d][n] via LDS
    if (g < 2) {
        const float ws = w * 256.0f;
#pragma unroll
        for (int t = 0; t < 8; ++t) {
            union { _Float16 h; ushort s; } a;
            a.h = (_Float16)(ws * (float)qf.h[t]);
            twq[koff + t][wv * 16 + i] = a.s;
        }
    }
    __syncthreads();
    {
        const int d = tt >> 4, seg = tt & 15;
        uint2 v;
        v.x = (uint32_t)twq[d][seg*4]   | ((uint32_t)twq[d][seg*4+1] << 16);
        v.y = (uint32_t)twq[d][seg*4+2] | ((uint32_t)twq[d][seg*4+3] << 16);
        *(uint2*)(WQT + ((size_t)(bh * 16 + d) << 11) + nblk * 64 + seg * 4) = v;
    }
}

// ---------------- colsum: R = M^T (256 w q), c = M^T (256 w) via mask-MFMA ----------------
// Full 1-iteration prefetch: maskM words, LUT expansions, wq fragment, wbf.
__global__ __launch_bounds__(256) void colsum_kernel(
    const ushort* __restrict__ WQT, const ushort* __restrict__ wbf,
    const uint32_t* __restrict__ maskM, float* __restrict__ R,
    float* __restrict__ cbuf)
{
    const int bid = blockIdx.x;
    const int bh  = ((bid & 7) << 2) | ((bid >> 3) & 3);   // XCD-local bh
    const int msb = bid >> 5;
    const int wv = threadIdx.x >> 6, lane = threadIdx.x & 63;
    const int i = lane & 15, g = lane >> 4;
    const int g8 = g << 3;
    const int mt0 = msb * 128 + wv * 16;
    const int mt1 = mt0 + 64;
    __shared__ uint2 LUT[16];
    __shared__ ushort wq[16][1040];
    if (threadIdx.x < 16) {
        uint32_t v = threadIdx.x;
        LUT[v] = make_uint2(
            ((v & 1u) ? 0xFFFFu : 0u) | ((v & 2u) ? 0xFFFF0000u : 0u),
            ((v & 4u) ? 0xFFFFu : 0u) | ((v & 8u) ? 0xFFFF0000u : 0u));
    }
    f32x4 aR0 = {0.f,0.f,0.f,0.f}, aR1 = {0.f,0.f,0.f,0.f};
    f32x4 aC0 = {0.f,0.f,0.f,0.f}, aC1 = {0.f,0.f,0.f,0.f};

    for (int half = 0; half < 2; ++half) {
        {   // stage WQT half-panel: [16 d][1024 n]
            int d = threadIdx.x >> 4, seg = (threadIdx.x & 15) * 64;
            const uint4* s = (const uint4*)(WQT + ((size_t)(bh * 16 + d) << 11)
                                            + half * 1024 + seg);
            uint4* dst = (uint4*)&wq[d][seg];
#pragma unroll
            for (int q = 0; q < 8; ++q) dst[q] = s[q];
        }
        __syncthreads();
        const int ub = half * 32;
        // prologue loads for uu = 0
        uint32_t w0 = maskM[(size_t)ub * 2048 + mt0 + i] >> g8;
        uint32_t w1 = maskM[(size_t)ub * 2048 + mt1 + i] >> g8;
        uint2 p0a = LUT[w0 & 15u], p0b = LUT[(w0 >> 4) & 15u];
        uint2 p1a = LUT[w1 & 15u], p1b = LUT[(w1 >> 4) & 15u];
        U4H8 b1; b1.u = *(const uint4*)&wq[i][g * 8];
        U4H8 b2; b2.u = make_uint4(0,0,0,0);
        if (i == 0) b2.u = *(const uint4*)(wbf + ((size_t)bh << 11) + half * 1024 + g * 8);

        for (int uu = 0; uu < 32; ++uu) {
            uint2 n0a = make_uint2(0,0), n0b = make_uint2(0,0);
            uint2 n1a = make_uint2(0,0), n1b = make_uint2(0,0);
            U4H8 nb1, nb2; nb1.u = make_uint4(0,0,0,0); nb2.u = make_uint4(0,0,0,0);
            if (uu < 31) {   // prefetch everything for uu+1
                const int un = ub + uu + 1;
                uint32_t x0 = maskM[(size_t)un * 2048 + mt0 + i] >> g8;
                uint32_t x1 = maskM[(size_t)un * 2048 + mt1 + i] >> g8;
                n0a = LUT[x0 & 15u]; n0b = LUT[(x0 >> 4) & 15u];
                n1a = LUT[x1 & 15u]; n1b = LUT[(x1 >> 4) & 15u];
                nb1.u = *(const uint4*)&wq[i][(uu + 1) * 32 + g * 8];
                if (i == 0) nb2.u = *(const uint4*)(wbf + ((size_t)bh << 11)
                                                    + half * 1024 + (uu + 1) * 32 + g * 8);
            }
            U4H8 af;
            af.u.x = p0a.x & ONE2; af.u.y = p0a.y & ONE2;
            af.u.z = p0b.x & ONE2; af.u.w = p0b.y & ONE2;
            aR0 = MFMAH(af.h, b1.h, aR0); aC0 = MFMAH(af.h, b2.h, aC0);
            af.u.x = p1a.x & ONE2; af.u.y = p1a.y & ONE2;
            af.u.z = p1b.x & ONE2; af.u.w = p1b.y & ONE2;
            aR1 = MFMAH(af.h, b1.h, aR1); aC1 = MFMAH(af.h, b2.h, aC1);
            p0a = n0a; p0b = n0b; p1a = n1a; p1b = n1b; b1 = nb1; b2 = nb2;
        }
        __syncthreads();
    }
#pragma unroll
    for (int r = 0; r < 4; ++r) {
        R[(((size_t)bh << 11) + mt0 + 4 * g + r) * 16 + i] = aR0[r];
        R[(((size_t)bh << 11) + mt1 + 4 * g + r) * 16 + i] = aR1[r];
    }
    if (i == 0) {
#pragma unroll
        for (int r = 0; r < 4; ++r) {
            cbuf[((size_t)bh << 11) + mt0 + 4 * g + r] = aC0[r];
            cbuf[((size_t)bh << 11) + mt1 + 4 * g + r] = aC1[r];
        }
    }
}

// ---------------- out-proj + ReLU + pooling -> per-chunk partials ----------------
__global__ __launch_bounds__(256) void pool_kernel(
    const float* __restrict__ O, const float* __restrict__ act,
    const float* __restrict__ Wo, const float* __restrict__ bo,
    float* __restrict__ gpart)
{
    int b  = blockIdx.x >> 5;
    int nc = blockIdx.x & 31;        // 64-node chunk
    int lane = threadIdx.x & 63;     // output channel j
    int sw   = threadIdx.x >> 6;

    __shared__ float o_lds[64][65];
    __shared__ float w_lds[64][65];
    for (int t = threadIdx.x; t < 4096; t += 256) {
        int r = t >> 6, e = t & 63;
        w_lds[r][e] = Wo[t];
        int h = e >> 4, d = e & 15;
        size_t base = (((size_t)b * NH + h) * NND + nc * 64 + r) * HDIM + d;
        o_lds[r][e] = O[base];
    }
    __syncthreads();

    float boj = bo[lane];
    float acc = 0.f;
    for (int i = 0; i < 16; ++i) {
        int nn = sw * 16 + i;
        float d0 = 0.f, d1 = 0.f;
#pragma unroll
        for (int e = 0; e < 64; e += 2) {
            d0 = fmaf(o_lds[nn][e],   w_lds[lane][e],   d0);
            d1 = fmaf(o_lds[nn][e+1], w_lds[lane][e+1], d1);
        }
        float r = fmaxf(d0 + d1 + boj, 0.f);
        acc = fmaf(r, act[(size_t)b * NND + nc * 64 + nn], acc);
    }
    __shared__ float red[4][64];
    red[sw][lane] = acc;
    __syncthreads();
    if (sw == 0) {
        float sum = (red[0][lane] + red[1][lane]) + (red[2][lane] + red[3][lane]);
        gpart[((size_t)(b * 32 + nc)) * 64 + lane] = sum;
    }
}

// ---------------- finalize: blocks 0-63 node_attention, 64-71 LayerNorm ----------------
__global__ __launch_bounds__(256) void final_kernel(
    const float* __restrict__ act, const float* __restrict__ gpart,
    const float* __restrict__ cbuf, const float* __restrict__ R,
    const ushort* __restrict__ Kf, const float* __restrict__ gamma,
    const float* __restrict__ beta, float* __restrict__ out)
{
    const int blk = blockIdx.x;
    const int t = threadIdx.x;
    if (blk < 64) {
        const int b = blk >> 3, mc = blk & 7;
        const int m = mc * 256 + t;
        const float sc = 1.0f / (256.0f * NH * (float)NND);
        float cs = 0.f;
#pragma unroll
        for (int h = 0; h < NH; ++h) {
            size_t idx = (((size_t)(b * NH + h)) << 11) + m;
            cs += cbuf[idx];
            const f32x4* rr = (const f32x4*)(R + (idx << 4));
            const uint4* kk = (const uint4*)(Kf + (idx << 4));
            U4H8 k0, k1; k0.u = kk[0]; k1.u = kk[1];
            f32x4 r0 = rr[0], r1 = rr[1], r2 = rr[2], r3 = rr[3];
            cs += (float)k0.h[0]*r0[0] + (float)k0.h[1]*r0[1]
                + (float)k0.h[2]*r0[2] + (float)k0.h[3]*r0[3]
                + (float)k0.h[4]*r1[0] + (float)k0.h[5]*r1[1]
                + (float)k0.h[6]*r1[2] + (float)k0.h[7]*r1[3]
                + (float)k1.h[0]*r2[0] + (float)k1.h[1]*r2[1]
                + (float)k1.h[2]*r2[2] + (float)k1.h[3]*r2[3]
                + (float)k1.h[4]*r3[0] + (float)k1.h[5]*r3[1]
                + (float)k1.h[6]*r3[2] + (float)k1.h[7]*r3[3];
        }
        size_t oi = (size_t)b * NND + m;
        out[(size_t)NB * 64 + oi] = cs * sc * act[oi];
        return;
    }
    const int b = blk - 64;
    __shared__ float red[256];
    float s = 0.f;
    for (int n = t; n < NND; n += 256) s += act[(size_t)b * NND + n];
    red[t] = s;
    __syncthreads();
    for (int off = 128; off > 0; off >>= 1) {
        if (t < off) red[t] += red[t + off];
        __syncthreads();
    }
    float inv = 1.0f / fmaxf(red[0], 1.0f);
    __syncthreads();

    __shared__ float gv[64];
    __shared__ float st[2];
    if (t < 64) {
        float sgl = 0.f;
        const float* gp = gpart + (size_t)b * 32 * 64 + t;
#pragma unroll
        for (int c = 0; c < 32; ++c) sgl += gp[c * 64];
        gv[t] = sgl * inv;
    }
    __syncthreads();
    if (t == 0) {
        float mu = 0.f;
        for (int jj = 0; jj < 64; ++jj) mu += gv[jj];
        mu *= (1.0f / 64.0f);
        float var = 0.f;
        for (int jj = 0; jj < 64; ++jj) { float d = gv[jj] - mu; var += d * d; }
        var *= (1.0f / 64.0f);
        st[0] = mu;
        st[1] = 1.0f / sqrtf(var + 1e-5f);
    }
    __syncthreads();
    if (t < 64) out[b * 64 + t] = (gv[t] - st[0]) * st[1] * gamma[t] + beta[t];
}

// ---------------- launch ----------------
extern "C" void kernel_launch(void* const* d_in, const int* in_sizes, int n_in,
                              void* d_out, int out_size, void* d_ws, size_t ws_size,
                              hipStream_t stream)
{
    const float* act   = (const float*)d_in[0];
    const int*   adj   = (const int*)d_in[1];
    const float* embed = (const float*)d_in[2];
    const float* Wq = (const float*)d_in[3];
    const float* bq = (const float*)d_in[4];
    const float* Wk = (const float*)d_in[5];
    const float* bk = (const float*)d_in[6];
    const float* Wv = (const float*)d_in[7];
    const float* bv = (const float*)d_in[8];
    const float* Wo = (const float*)d_in[9];
    const float* bo = (const float*)d_in[10];
    const float* gamma = (const float*)d_in[11];
    const float* beta  = (const float*)d_in[12];
    float* out = (float*)d_out;

    float* ws = (float*)d_ws;
    ushort* Qf  = (ushort*)(ws + OFF_QF);
    ushort* Kf  = (ushort*)(ws + OFF_KF);
    ushort* Vt  = (ushort*)(ws + OFF_VT);
    float*  O   = ws + OFF_O;
    float*  R   = ws + OFF_R;
    float*  cb  = ws + OFF_C;
    ushort* WQT = (ushort*)(ws + OFF_WQT);
    ushort* wbf = (ushort*)(ws + OFF_WBF);
    float*  gp  = ws + OFF_GP;
    uint32_t* maskT2 = (uint32_t*)(ws + OFF_MT2);
    uint32_t* maskM  = (uint32_t*)(ws + OFF_MM);

    qkv_kernel<<<NB * 128, 64, 0, stream>>>(act, embed, Wq, bq, Wk, bk, Wv, bv,
                                            Qf, Kf, Vt);
    mask_kernel<<<1024, 256, 0, stream>>>(adj, maskT2, maskM);
    attn_a_kernel<<<1024, 256, 0, stream>>>(Qf, Kf, Vt, maskT2, O, WQT, wbf);
    colsum_kernel<<<512, 256, 0, stream>>>(WQT, wbf, maskM, R, cb);
    pool_kernel<<<NB * 32, 256, 0, stream>>>(O, act, Wo, bo, gp);
    final_kernel<<<72, 256, 0, stream>>>(act, gp, cb, R, Kf, gamma, beta, out);
}

// Round 11
// 83.481 us; speedup vs baseline: 1.2919x; 1.2919x over previous
//
#include <hip/hip_runtime.h>
#include <stdint.h>

#define NND 2048   // nodes
#define NE  32     // embed
#define NH  4      // heads
#define HDIM 16    // head dim
#define NB  8      // batch

typedef __attribute__((ext_vector_type(4))) float f32x4;
typedef _Float16 f16x8 __attribute__((ext_vector_type(8)));
typedef _Float16 h16x2 __attribute__((ext_vector_type(2)));
typedef __fp16 fp16x2 __attribute__((ext_vector_type(2)));

#define MFMAH(a,b,c) __builtin_amdgcn_mfma_f32_16x16x32_f16(a,b,c,0,0,0)

// ---------------- workspace layout (in float units) ----------------
static constexpr size_t OFF_QF    = 0;
static constexpr size_t OFF_KF    = 524288;
static constexpr size_t OFF_VT    = 1048576;
static constexpr size_t OFF_O     = 1572864;
static constexpr size_t OFF_R     = 2621440;
static constexpr size_t OFF_C     = 3670016;           // 65536
static constexpr size_t OFF_WQT   = 3866624;           // 524288
static constexpr size_t OFF_WBF   = 4390912;           // 32768
static constexpr size_t OFF_MT2   = 4424192;           // maskT2: [16 nb][64 u][128 n] u32 = 131072 f
static constexpr size_t OFF_MM    = 4555264;           // maskM: 131072 f
static constexpr size_t OFF_GP    = 4686336;           // gpart: [8 b][32 nc][64] = 16384 f

// ---------------- helpers ----------------
__device__ __forceinline__ uint32_t f2h2(float a, float b) {
    union { _Float16 h[2]; uint32_t u; } x;
    x.h[0] = (_Float16)a; x.h[1] = (_Float16)b; return x.u;
}
__device__ __forceinline__ uint32_t pkh(float a, float b) {
    union { fp16x2 h; uint32_t u; } x;
    x.h = __builtin_amdgcn_cvt_pkrtz(a, b); return x.u;
}
union U4H8 { uint4 u; f16x8 h; };
union U1H2 { uint32_t u; h16x2 h; };

#define ONE2 0x3C003C00u

// ---------------- fused: qkv (blocks 0-255, 4 chunk-waves each) + mask (256-1279) ----------------
__global__ __launch_bounds__(256) void qkvmask_kernel(
    const float* __restrict__ act, const float* __restrict__ embed,
    const float* __restrict__ Wq, const float* __restrict__ bq,
    const float* __restrict__ Wk, const float* __restrict__ bk,
    const float* __restrict__ Wv, const float* __restrict__ bv,
    const int* __restrict__ adj,
    ushort* __restrict__ Qf, ushort* __restrict__ Kf, ushort* __restrict__ Vt,
    uint32_t* __restrict__ maskT2, uint32_t* __restrict__ maskM)
{
    __shared__ float x[4][16][33];
    __shared__ float qs[4][16][65], ks[4][16][65], vs[4][16][65];
    __shared__ unsigned char ld[64][68];
    const int bid = blockIdx.x;

    if (bid < 256) {
        // ---- qkv path: wave wvi handles 16-node chunk blk = bid*4+wvi ----
        const int wvi = threadIdx.x >> 6, j = threadIdx.x & 63;
        const int blk = (bid << 2) | wvi;
        const int b = blk >> 7, nc = blk & 127;

        float wq[NE], wk[NE], wv[NE];
        const float4* Wq4 = (const float4*)Wq;
        const float4* Wk4 = (const float4*)Wk;
        const float4* Wv4 = (const float4*)Wv;
#pragma unroll
        for (int t = 0; t < 8; ++t) {
            float4 a4 = Wq4[j * 8 + t];
            wq[4*t] = a4.x; wq[4*t+1] = a4.y; wq[4*t+2] = a4.z; wq[4*t+3] = a4.w;
            float4 b4 = Wk4[j * 8 + t];
            wk[4*t] = b4.x; wk[4*t+1] = b4.y; wk[4*t+2] = b4.z; wk[4*t+3] = b4.w;
            float4 c4 = Wv4[j * 8 + t];
            wv[4*t] = c4.x; wv[4*t+1] = c4.y; wv[4*t+2] = c4.z; wv[4*t+3] = c4.w;
        }
        const float bqj = bq[j], bkj = bk[j], bvj = bv[j];

        const float4* E4 = (const float4*)(embed + (size_t)nc * 16 * NE);
#pragma unroll
        for (int tt = 0; tt < 2; ++tt) {
            int t = tt * 64 + j;
            float4 e4 = E4[t];
            int row = t >> 3, col = (t & 7) * 4;
            float a = act[(size_t)b * NND + nc * 16 + row];
            x[wvi][row][col+0] = e4.x * a; x[wvi][row][col+1] = e4.y * a;
            x[wvi][row][col+2] = e4.z * a; x[wvi][row][col+3] = e4.w * a;
        }
        __syncthreads();

        for (int ii = 0; ii < 16; ++ii) {
            float q = bqj, k = bkj, v = bvj;
#pragma unroll
            for (int e = 0; e < NE; ++e) {
                float xe = x[wvi][ii][e];
                q = fmaf(wq[e], xe, q);
                k = fmaf(wk[e], xe, k);
                v = fmaf(wv[e], xe, v);
            }
            qs[wvi][ii][j] = q * 0.25f;   // fold 1/sqrt(HD)
            ks[wvi][ii][j] = k;
            vs[wvi][ii][j] = v;
        }
        __syncthreads();

        const int c = j >> 4, ii = j & 15;
        {
            size_t row = ((size_t)(b*NH + c) << 11) + (nc << 4) + ii;
            uint32_t pk[8], pq[8];
#pragma unroll
            for (int t = 0; t < 8; ++t) {
                pk[t] = f2h2(ks[wvi][ii][c*16 + 2*t], ks[wvi][ii][c*16 + 2*t + 1]);
                pq[t] = f2h2(qs[wvi][ii][c*16 + 2*t], qs[wvi][ii][c*16 + 2*t + 1]);
            }
            uint4* dk = (uint4*)(Kf + row * 16);
            dk[0] = make_uint4(pk[0], pk[1], pk[2], pk[3]);
            dk[1] = make_uint4(pk[4], pk[5], pk[6], pk[7]);
            uint4* dq = (uint4*)(Qf + row * 16);
            dq[0] = make_uint4(pq[0], pq[1], pq[2], pq[3]);
            dq[1] = make_uint4(pq[4], pq[5], pq[6], pq[7]);
        }
        {
            uint32_t ph[8];
#pragma unroll
            for (int t = 0; t < 8; ++t)
                ph[t] = f2h2(vs[wvi][2*t][j], vs[wvi][2*t + 1][j]);
            size_t rowv = (((size_t)(b*NH + c) << 4) + ii) * 2048 + (nc << 4);
            uint4* dh = (uint4*)(Vt + rowv);
            dh[0] = make_uint4(ph[0], ph[1], ph[2], ph[3]);
            dh[1] = make_uint4(ph[4], ph[5], ph[6], ph[7]);
        }
        return;
    }

    // ---- mask path ----
    const int mblk = bid - 256;
    const int nb = mblk >> 5, mb = mblk & 31;
    const int n0 = nb * 64, m0 = mb * 64;
    const int t = threadIdx.x;
    const int r = t >> 2, cs = (t & 3) * 16;
    const int4* src = (const int4*)(adj + (size_t)(n0 + r) * 2048 + m0 + cs);
    int4 a0 = src[0], a1 = src[1], a2 = src[2], a3 = src[3];
    unsigned char* dst = &ld[r][cs];
    dst[0]=a0.x!=0; dst[1]=a0.y!=0; dst[2]=a0.z!=0; dst[3]=a0.w!=0;
    dst[4]=a1.x!=0; dst[5]=a1.y!=0; dst[6]=a1.z!=0; dst[7]=a1.w!=0;
    dst[8]=a2.x!=0; dst[9]=a2.y!=0; dst[10]=a2.z!=0; dst[11]=a2.w!=0;
    dst[12]=a3.x!=0; dst[13]=a3.y!=0; dst[14]=a3.z!=0; dst[15]=a3.w!=0;
    __syncthreads();
    const int wv = t >> 6, lane = t & 63;
#pragma unroll 4
    for (int q = 0; q < 16; ++q) {
        int rr = wv * 16 + q;
        unsigned long long bm = __ballot(ld[rr][lane] != 0);
        if (lane == 0) {
            // maskT2[nb2][u][128 n]: nb2 = nb>>1, nloc = (nb&1)*64 + rr
            size_t base = (size_t)(nb >> 1) * 8192 + (size_t)(nb & 1) * 64 + rr;
            maskT2[base + (size_t)(m0 >> 5) * 128]       = (uint32_t)bm;
            maskT2[base + (size_t)((m0 >> 5) + 1) * 128] = (uint32_t)(bm >> 32);
        }
    }
#pragma unroll 4
    for (int q = 0; q < 16; ++q) {
        int cc = wv * 16 + q;
        unsigned long long bm = __ballot(ld[lane][cc] != 0);
        if (lane == 0) {
            maskM[(size_t)(n0 >> 5) * 2048 + m0 + cc]       = (uint32_t)bm;
            maskM[(size_t)((n0 >> 5) + 1) * 2048 + m0 + cc] = (uint32_t)(bm >> 32);
        }
    }
}

// ---------------- fused attention: 128-n blocks (8 waves), group-of-4 staging ----------------
__global__ __launch_bounds__(512) void attn_a_kernel(
    const ushort* __restrict__ Qf, const ushort* __restrict__ Kf,
    const ushort* __restrict__ Vt, const uint32_t* __restrict__ maskT2,
    float* __restrict__ O, ushort* __restrict__ WQT, ushort* __restrict__ wbf)
{
    const int bid = blockIdx.x;                              // 512 blocks
    const int bh   = ((bid & 7) << 2) | ((bid >> 3) & 3);    // XCD-local bh
    const int nblk = bid >> 5;                               // 0..15 (128-n tiles)
    const int tt = threadIdx.x;
    const int wv = tt >> 6, lane = tt & 63;
    const int i = lane & 15, g = lane >> 4;
    const int g8 = g << 3;
    const int n = nblk * 128 + wv * 16 + i;
    const int fi = ((i >> 2) << 3) | (i & 3);
    const int koff = (g & 1) * 8;

    __shared__ ushort Kg[2][2048];       // 128 rows x 16 ushorts, linear
    __shared__ ushort Vg[2][2176];       // 16 d x 136 ushorts (128 m + 8 pad)
    __shared__ uint32_t Mg[2][512];      // 4 chunks x 128 n-words
    __shared__ uint2 LUT[16];
    __shared__ ushort twq[16][136];

    if (tt < 16) {
        uint32_t v = tt;
        LUT[v] = make_uint2(
            ((v & 1u) ? 0xFFFFu : 0u) | ((v & 2u) ? 0xFFFF0000u : 0u),
            ((v & 4u) ? 0xFFFFu : 0u) | ((v & 8u) ? 0xFFFF0000u : 0u));
    }

    const ushort* Kb = Kf + (((size_t)bh << 11) << 4);
    const ushort* ksrc = Kb + tt * 4;                                        // + m0*16/group
    const ushort* vsrc = Vt + (((size_t)bh * 16 + (tt & 15)) << 11) + ((tt >> 4) << 2); // + m0/group
    const uint32_t* msrc = maskT2 + (size_t)nblk * 8192;                     // + grp*512 + tt
    const int vdst = (tt & 15) * 136 + ((tt >> 4) << 2);

    U4H8 qf; qf.u = make_uint4(0,0,0,0);
    if (g < 2) qf.u = *(const uint4*)(Qf + ((((size_t)bh << 11) + n) << 4) + koff);
    f32x4 oacc = {0.f,0.f,0.f,0.f};
    float lsum = 0.f;
    const f32x4 zc = {0.f,0.f,0.f,0.f};

    // prologue: stage group 0
    uint2 rk = *(const uint2*)ksrc;
    uint2 rv = *(const uint2*)vsrc;
    uint32_t rm = msrc[tt];
    *(uint2*)&Kg[0][tt * 4] = rk;
    *(uint2*)&Vg[0][vdst] = rv;
    Mg[0][tt] = rm;
    __syncthreads();

    const int mi = (wv << 4) + i;
    for (int grp = 0; grp < 16; ++grp) {
        const int buf = grp & 1;
        if (grp < 15) {   // issue next-group loads first (hide under compute)
            const int m0 = (grp + 1) << 7;
            rk = *(const uint2*)(ksrc + ((size_t)m0 << 4));
            rv = *(const uint2*)(vsrc + m0);
            rm = msrc[(grp + 1) * 512 + tt];
        }
        // hoist mask words + LUT expansions for all 4 chunks
        const uint32_t mg0 = Mg[buf][mi]       >> g8;
        const uint32_t mg1 = Mg[buf][128 + mi] >> g8;
        const uint32_t mg2 = Mg[buf][256 + mi] >> g8;
        const uint32_t mg3 = Mg[buf][384 + mi] >> g8;
        const uint2 e0a = LUT[mg0 & 15u], e0b = LUT[(mg0 >> 4) & 15u];
        const uint2 e1a = LUT[mg1 & 15u], e1b = LUT[(mg1 >> 4) & 15u];
        const uint2 e2a = LUT[mg2 & 15u], e2b = LUT[(mg2 >> 4) & 15u];
        const uint2 e3a = LUT[mg3 & 15u], e3b = LUT[(mg3 >> 4) & 15u];
        lsum += (float)__popc((mg0 & 0xFFu) | ((mg1 & 0xFFu) << 8)
                            | ((mg2 & 0xFFu) << 16) | ((mg3 & 0xFFu) << 24));

#define CHUNK(J, EA, EB) do { \
            U4H8 ka, kb, vh; \
            ka.u = *(const uint4*)&Kg[buf][(((J) * 32 + fi) << 4) + koff]; \
            kb.u = *(const uint4*)&Kg[buf][(((J) * 32 + fi + 4) << 4) + koff]; \
            vh.u = *(const uint4*)&Vg[buf][i * 136 + (J) * 32 + g8]; \
            f32x4 ca = MFMAH(ka.h, qf.h, zc); \
            f32x4 cb = MFMAH(kb.h, qf.h, zc); \
            U4H8 mf, tf; \
            mf.u.x = EA.x & ONE2;  mf.u.y = EA.y & ONE2; \
            mf.u.z = EB.x & ONE2;  mf.u.w = EB.y & ONE2; \
            tf.u.x = pkh(ca[0], ca[1]) & EA.x; \
            tf.u.y = pkh(ca[2], ca[3]) & EA.y; \
            tf.u.z = pkh(cb[0], cb[1]) & EB.x; \
            tf.u.w = pkh(cb[2], cb[3]) & EB.y; \
            U1H2 h0, h1, h2, h3, hs; \
            h0.u = tf.u.x; h1.u = tf.u.y; h2.u = tf.u.z; h3.u = tf.u.w; \
            hs.h = (h0.h + h1.h) + (h2.h + h3.h); \
            lsum += (float)hs.h[0] + (float)hs.h[1]; \
            oacc = MFMAH(vh.h, mf.h, oacc); \
            oacc = MFMAH(vh.h, tf.h, oacc); \
        } while (0)

        CHUNK(0, e0a, e0b);
        CHUNK(1, e1a, e1b);
        CHUNK(2, e2a, e2b);
        CHUNK(3, e3a, e3b);
#undef CHUNK

        if (grp < 15) {   // write staged data into the other buffer
            *(uint2*)&Kg[buf ^ 1][tt * 4] = rk;
            *(uint2*)&Vg[buf ^ 1][vdst] = rv;
            Mg[buf ^ 1][tt] = rm;
        }
        __syncthreads();
    }

    lsum += __shfl_xor(lsum, 16);
    lsum += __shfl_xor(lsum, 32);
    const float w = 1.0f / lsum;
    f32x4 ov;
    ov[0] = oacc[0] * w; ov[1] = oacc[1] * w;
    ov[2] = oacc[2] * w; ov[3] = oacc[3] * w;
    *(f32x4*)(O + ((((size_t)bh << 11) + n) << 4) + (g << 2)) = ov;
    if (g == 0) {
        union { _Float16 h; ushort s; } cw; cw.h = (_Float16)(w * 256.0f);
        wbf[((size_t)bh << 11) + n] = cw.s;
    }
    // WQT = 256*w*q, transposed to [d][n] via LDS
    if (g < 2) {
        const float ws = w * 256.0f;
#pragma unroll
        for (int t = 0; t < 8; ++t) {
            union { _Float16 h; ushort s; } a;
            a.h = (_Float16)(ws * (float)qf.h[t]);
            twq[koff + t][wv * 16 + i] = a.s;
        }
    }
    __syncthreads();
    {
        const int d = tt >> 5, seg = tt & 31;
        uint2 v;
        v.x = (uint32_t)twq[d][seg*4]   | ((uint32_t)twq[d][seg*4+1] << 16);
        v.y = (uint32_t)twq[d][seg*4+2] | ((uint32_t)twq[d][seg*4+3] << 16);
        *(uint2*)(WQT + ((size_t)(bh * 16 + d) << 11) + nblk * 128 + seg * 4) = v;
    }
}

// ---------------- fused: colsum (blocks 0-511) + pool (512-767) ----------------
static constexpr int SMEM_SZ = 34304;
__global__ __launch_bounds__(256) void colsumpool_kernel(
    const ushort* __restrict__ WQT, const ushort* __restrict__ wbf,
    const uint32_t* __restrict__ maskM, float* __restrict__ R,
    float* __restrict__ cbuf,
    const float* __restrict__ O, const float* __restrict__ act,
    const float* __restrict__ Wo, const float* __restrict__ bo,
    float* __restrict__ gpart)
{
    __shared__ __align__(16) unsigned char smem[SMEM_SZ];
    const int bid = blockIdx.x;

    if (bid < 512) {
        // ---- colsum path ----
        uint2* LUT = (uint2*)smem;                          // 128 B
        ushort (*wq)[1040] = (ushort(*)[1040])(smem + 128); // 33280 B
        const int bh  = ((bid & 7) << 2) | ((bid >> 3) & 3);
        const int msb = bid >> 5;
        const int wv = threadIdx.x >> 6, lane = threadIdx.x & 63;
        const int i = lane & 15, g = lane >> 4;
        const int g8 = g << 3;
        const int mt0 = msb * 128 + wv * 16;
        const int mt1 = mt0 + 64;
        if (threadIdx.x < 16) {
            uint32_t v = threadIdx.x;
            LUT[v] = make_uint2(
                ((v & 1u) ? 0xFFFFu : 0u) | ((v & 2u) ? 0xFFFF0000u : 0u),
                ((v & 4u) ? 0xFFFFu : 0u) | ((v & 8u) ? 0xFFFF0000u : 0u));
        }
        f32x4 aR0 = {0.f,0.f,0.f,0.f}, aR1 = {0.f,0.f,0.f,0.f};
        f32x4 aC0 = {0.f,0.f,0.f,0.f}, aC1 = {0.f,0.f,0.f,0.f};

        for (int half = 0; half < 2; ++half) {
            {   // stage WQT half-panel: [16 d][1024 n]
                int d = threadIdx.x >> 4, seg = (threadIdx.x & 15) * 64;
                const uint4* s = (const uint4*)(WQT + ((size_t)(bh * 16 + d) << 11)
                                                + half * 1024 + seg);
                uint4* dstp = (uint4*)&wq[d][seg];
#pragma unroll
                for (int q = 0; q < 8; ++q) dstp[q] = s[q];
            }
            __syncthreads();
            const int ub = half * 32;
            uint32_t w0 = maskM[(size_t)ub * 2048 + mt0 + i] >> g8;
            uint32_t w1 = maskM[(size_t)ub * 2048 + mt1 + i] >> g8;
            uint2 p0a = LUT[w0 & 15u], p0b = LUT[(w0 >> 4) & 15u];
            uint2 p1a = LUT[w1 & 15u], p1b = LUT[(w1 >> 4) & 15u];
            U4H8 b1; b1.u = *(const uint4*)&wq[i][g * 8];
            U4H8 b2; b2.u = make_uint4(0,0,0,0);
            if (i == 0) b2.u = *(const uint4*)(wbf + ((size_t)bh << 11) + half * 1024 + g * 8);

            for (int uu = 0; uu < 32; ++uu) {
                uint2 n0a = make_uint2(0,0), n0b = make_uint2(0,0);
                uint2 n1a = make_uint2(0,0), n1b = make_uint2(0,0);
                U4H8 nb1, nb2; nb1.u = make_uint4(0,0,0,0); nb2.u = make_uint4(0,0,0,0);
                if (uu < 31) {
                    const int un = ub + uu + 1;
                    uint32_t x0 = maskM[(size_t)un * 2048 + mt0 + i] >> g8;
                    uint32_t x1 = maskM[(size_t)un * 2048 + mt1 + i] >> g8;
                    n0a = LUT[x0 & 15u]; n0b = LUT[(x0 >> 4) & 15u];
                    n1a = LUT[x1 & 15u]; n1b = LUT[(x1 >> 4) & 15u];
                    nb1.u = *(const uint4*)&wq[i][(uu + 1) * 32 + g * 8];
                    if (i == 0) nb2.u = *(const uint4*)(wbf + ((size_t)bh << 11)
                                                        + half * 1024 + (uu + 1) * 32 + g * 8);
                }
                U4H8 af;
                af.u.x = p0a.x & ONE2; af.u.y = p0a.y & ONE2;
                af.u.z = p0b.x & ONE2; af.u.w = p0b.y & ONE2;
                aR0 = MFMAH(af.h, b1.h, aR0); aC0 = MFMAH(af.h, b2.h, aC0);
                af.u.x = p1a.x & ONE2; af.u.y = p1a.y & ONE2;
                af.u.z = p1b.x & ONE2; af.u.w = p1b.y & ONE2;
                aR1 = MFMAH(af.h, b1.h, aR1); aC1 = MFMAH(af.h, b2.h, aC1);
                p0a = n0a; p0b = n0b; p1a = n1a; p1b = n1b; b1 = nb1; b2 = nb2;
            }
            __syncthreads();
        }
#pragma unroll
        for (int r = 0; r < 4; ++r) {
            R[(((size_t)bh << 11) + mt0 + 4 * g + r) * 16 + i] = aR0[r];
            R[(((size_t)bh << 11) + mt1 + 4 * g + r) * 16 + i] = aR1[r];
        }
        if (i == 0) {
#pragma unroll
            for (int r = 0; r < 4; ++r) {
                cbuf[((size_t)bh << 11) + mt0 + 4 * g + r] = aC0[r];
                cbuf[((size_t)bh << 11) + mt1 + 4 * g + r] = aC1[r];
            }
        }
        return;
    }

    // ---- pool path ----
    float (*o_lds)[65] = (float(*)[65])smem;                 // 16640 B
    float (*w_lds)[65] = (float(*)[65])(smem + 16640);       // 16640 B
    float (*red)[64]   = (float(*)[64])(smem + 33280);       // 1024 B
    const int pblk = bid - 512;
    int b  = pblk >> 5;
    int nc = pblk & 31;
    int lane = threadIdx.x & 63;
    int sw   = threadIdx.x >> 6;

    for (int t = threadIdx.x; t < 4096; t += 256) {
        int r = t >> 6, e = t & 63;
        w_lds[r][e] = Wo[t];
        int h = e >> 4, d = e & 15;
        size_t base = (((size_t)b * NH + h) * NND + nc * 64 + r) * HDIM + d;
        o_lds[r][e] = O[base];
    }
    __syncthreads();

    float boj = bo[lane];
    float acc = 0.f;
    for (int i = 0; i < 16; ++i) {
        int nn = sw * 16 + i;
        float d0 = 0.f, d1 = 0.f;
#pragma unroll
        for (int e = 0; e < 64; e += 2) {
            d0 = fmaf(o_lds[nn][e],   w_lds[lane][e],   d0);
            d1 = fmaf(o_lds[nn][e+1], w_lds[lane][e+1], d1);
        }
        float r = fmaxf(d0 + d1 + boj, 0.f);
        acc = fmaf(r, act[(size_t)b * NND + nc * 64 + nn], acc);
    }
    red[sw][lane] = acc;
    __syncthreads();
    if (sw == 0) {
        float sum = (red[0][lane] + red[1][lane]) + (red[2][lane] + red[3][lane]);
        gpart[((size_t)(b * 32 + nc)) * 64 + lane] = sum;
    }
}

// ---------------- finalize: blocks 0-63 node_attention, 64-71 LayerNorm ----------------
__global__ __launch_bounds__(256) void final_kernel(
    const float* __restrict__ act, const float* __restrict__ gpart,
    const float* __restrict__ cbuf, const float* __restrict__ R,
    const ushort* __restrict__ Kf, const float* __restrict__ gamma,
    const float* __restrict__ beta, float* __restrict__ out)
{
    const int blk = blockIdx.x;
    const int t = threadIdx.x;
    if (blk < 64) {
        const int b = blk >> 3, mc = blk & 7;
        const int m = mc * 256 + t;
        const float sc = 1.0f / (256.0f * NH * (float)NND);
        float cs = 0.f;
#pragma unroll
        for (int h = 0; h < NH; ++h) {
            size_t idx = (((size_t)(b * NH + h)) << 11) + m;
            cs += cbuf[idx];
            const f32x4* rr = (const f32x4*)(R + (idx << 4));
            const uint4* kk = (const uint4*)(Kf + (idx << 4));
            U4H8 k0, k1; k0.u = kk[0]; k1.u = kk[1];
            f32x4 r0 = rr[0], r1 = rr[1], r2 = rr[2], r3 = rr[3];
            cs += (float)k0.h[0]*r0[0] + (float)k0.h[1]*r0[1]
                + (float)k0.h[2]*r0[2] + (float)k0.h[3]*r0[3]
                + (float)k0.h[4]*r1[0] + (float)k0.h[5]*r1[1]
                + (float)k0.h[6]*r1[2] + (float)k0.h[7]*r1[3]
                + (float)k1.h[0]*r2[0] + (float)k1.h[1]*r2[1]
                + (float)k1.h[2]*r2[2] + (float)k1.h[3]*r2[3]
                + (float)k1.h[4]*r3[0] + (float)k1.h[5]*r3[1]
                + (float)k1.h[6]*r3[2] + (float)k1.h[7]*r3[3];
        }
        size_t oi = (size_t)b * NND + m;
        out[(size_t)NB * 64 + oi] = cs * sc * act[oi];
        return;
    }
    const int b = blk - 64;
    __shared__ float red[256];
    float s = 0.f;
    for (int n = t; n < NND; n += 256) s += act[(size_t)b * NND + n];
    red[t] = s;
    __syncthreads();
    for (int off = 128; off > 0; off >>= 1) {
        if (t < off) red[t] += red[t + off];
        __syncthreads();
    }
    float inv = 1.0f / fmaxf(red[0], 1.0f);
    __syncthreads();

    __shared__ float gv[64];
    __shared__ float st[2];
    if (t < 64) {
        float sgl = 0.f;
        const float* gp = gpart + (size_t)b * 32 * 64 + t;
#pragma unroll
        for (int c = 0; c < 32; ++c) sgl += gp[c * 64];
        gv[t] = sgl * inv;
    }
    __syncthreads();
    if (t == 0) {
        float mu = 0.f;
        for (int jj = 0; jj < 64; ++jj) mu += gv[jj];
        mu *= (1.0f / 64.0f);
        float var = 0.f;
        for (int jj = 0; jj < 64; ++jj) { float d = gv[jj] - mu; var += d * d; }
        var *= (1.0f / 64.0f);
        st[0] = mu;
        st[1] = 1.0f / sqrtf(var + 1e-5f);
    }
    __syncthreads();
    if (t < 64) out[b * 64 + t] = (gv[t] - st[0]) * st[1] * gamma[t] + beta[t];
}

// ---------------- launch ----------------
extern "C" void kernel_launch(void* const* d_in, const int* in_sizes, int n_in,
                              void* d_out, int out_size, void* d_ws, size_t ws_size,
                              hipStream_t stream)
{
    const float* act   = (const float*)d_in[0];
    const int*   adj   = (const int*)d_in[1];
    const float* embed = (const float*)d_in[2];
    const float* Wq = (const float*)d_in[3];
    const float* bq = (const float*)d_in[4];
    const float* Wk = (const float*)d_in[5];
    const float* bk = (const float*)d_in[6];
    const float* Wv = (const float*)d_in[7];
    const float* bv = (const float*)d_in[8];
    const float* Wo = (const float*)d_in[9];
    const float* bo = (const float*)d_in[10];
    const float* gamma = (const float*)d_in[11];
    const float* beta  = (const float*)d_in[12];
    float* out = (float*)d_out;

    float* ws = (float*)d_ws;
    ushort* Qf  = (ushort*)(ws + OFF_QF);
    ushort* Kf  = (ushort*)(ws + OFF_KF);
    ushort* Vt  = (ushort*)(ws + OFF_VT);
    float*  O   = ws + OFF_O;
    float*  R   = ws + OFF_R;
    float*  cb  = ws + OFF_C;
    ushort* WQT = (ushort*)(ws + OFF_WQT);
    ushort* wbf = (ushort*)(ws + OFF_WBF);
    float*  gp  = ws + OFF_GP;
    uint32_t* maskT2 = (uint32_t*)(ws + OFF_MT2);
    uint32_t* maskM  = (uint32_t*)(ws + OFF_MM);

    qkvmask_kernel<<<1280, 256, 0, stream>>>(act, embed, Wq, bq, Wk, bk, Wv, bv,
                                             adj, Qf, Kf, Vt, maskT2, maskM);
    attn_a_kernel<<<512, 512, 0, stream>>>(Qf, Kf, Vt, maskT2, O, WQT, wbf);
    colsumpool_kernel<<<768, 256, 0, stream>>>(WQT, wbf, maskM, R, cb,
                                               O, act, Wo, bo, gp);
    final_kernel<<<72, 256, 0, stream>>>(act, gp, cb, R, Kf, gamma, beta, out);
}